// Round 2
// 865.039 us; speedup vs baseline: 1.0831x; 1.0831x over previous
//
#include <hip/hip_runtime.h>

// ---------- types / helpers ----------
typedef __attribute__((ext_vector_type(8))) _Float16 f16x8;
typedef __attribute__((ext_vector_type(2))) _Float16 h2;
typedef __attribute__((ext_vector_type(4))) float f32x4;
typedef __attribute__((ext_vector_type(2))) float f32x2;
typedef __attribute__((ext_vector_type(4))) unsigned uint4_t;
typedef __attribute__((ext_vector_type(2))) unsigned uint2_t;

__device__ __forceinline__ h2 pkrtz(float a, float b) {
    // builtin returns __fp16 ext_vector(2); bit_cast to our _Float16-based h2
    return __builtin_bit_cast(h2, __builtin_amdgcn_cvt_pkrtz(a, b));   // v_cvt_pkrtz_f16_f32
}
__device__ __forceinline__ unsigned h2u(h2 v) { return __builtin_bit_cast(unsigned, v); }
__device__ __forceinline__ h2 u2h(unsigned u) { return __builtin_bit_cast(h2, u); }
__device__ __forceinline__ short f2h(float f) { return __builtin_bit_cast(short, (_Float16)f); }

// ws layout (bytes)
#define OFF_W1T 0L            // 32768
#define OFF_W2T 32768L        // 16384
#define OFF_W3T 49152L        // 32768
#define OFF_W4T 81920L        // 16384
#define OFF_DWH 98304L        // 4608
#define OFF_DBH 102912L       // 512
#define OFF_WATT 103424L      // 4096
#define OFF_GPART 107520L     // 524288
#define OFF_T 631808L         // 134217728

// ---------- K0: weight transpose + fp16 cast ----------
__global__ __launch_bounds__(256) void k_prep(
    const float* __restrict__ w1, const float* __restrict__ w2,
    const float* __restrict__ w3, const float* __restrict__ w4,
    const float* __restrict__ dww, const float* __restrict__ dwb,
    short* __restrict__ w1t, short* __restrict__ w2t,
    short* __restrict__ w3t, short* __restrict__ w4t,
    short* __restrict__ dwh, short* __restrict__ dbh)
{
    int id = blockIdx.x * 256 + threadIdx.x;
    if (id < 64 * 256) {
        int ci = id >> 8, co = id & 255;
        w1t[co * 64 + ci] = f2h(w1[id]);
        w3t[co * 64 + ci] = f2h(w3[id]);
    }
    if (id < 128 * 64) {
        int ci = id >> 6, co = id & 63;
        w2t[co * 128 + ci] = f2h(w2[id]);
        w4t[co * 128 + ci] = f2h(w4[id]);
    }
    if (id < 9 * 256) dwh[id] = f2h(dww[id]);
    if (id < 256)     dbh[id] = f2h(dwb[id]);
}

// ---------- K_A ----------
#define UST 136
__global__ __launch_bounds__(256) void k_a(
    const float* __restrict__ x, const float* __restrict__ ln1g, const float* __restrict__ ln1b,
    const short* __restrict__ w1t, const float* __restrict__ b1,
    const short* __restrict__ dwh, const short* __restrict__ dbh,
    short* __restrict__ t)
{
    __shared__ short uh[100 * UST];
    const int blk = blockIdx.x;
    const int cs  = blk & 1;
    const int txy = blk >> 1;
    const int tx  = txy & 31;
    const int ty  = (txy >> 5) & 31;
    const int b   = txy >> 10;
    const int tid = threadIdx.x;
    const int lane = tid & 63;
    const int wave = tid >> 6;
    const int m    = lane & 15;
    const int quad = lane >> 4;

    for (int tt = wave; tt < 7; tt += 4) {
        int p  = tt * 16 + m;
        int hy = (p * 205) >> 11;
        int hx = p - hy * 10;
        int gy = ty * 8 + hy - 1, gx = tx * 8 + hx - 1;
        bool pin = (p < 100);
        bool img = pin && gy >= 0 && gy < 256 && gx >= 0 && gx < 256;

        f16x8 a0 = {0,0,0,0,0,0,0,0}, a1 = {0,0,0,0,0,0,0,0};
        if (img) {
            const float* xr = x + ((long)((b * 256 + gy) * 256 + gx)) * 64;
            f32x4 f0 = *(const f32x4*)(xr + quad * 8);
            f32x4 f1 = *(const f32x4*)(xr + quad * 8 + 4);
            f32x4 f2 = *(const f32x4*)(xr + 32 + quad * 8);
            f32x4 f3 = *(const f32x4*)(xr + 32 + quad * 8 + 4);
            float s  = (f0[0]+f0[1]+f0[2]+f0[3]) + (f1[0]+f1[1]+f1[2]+f1[3])
                     + (f2[0]+f2[1]+f2[2]+f2[3]) + (f3[0]+f3[1]+f3[2]+f3[3]);
            float s2 = (f0[0]*f0[0]+f0[1]*f0[1]+f0[2]*f0[2]+f0[3]*f0[3])
                     + (f1[0]*f1[0]+f1[1]*f1[1]+f1[2]*f1[2]+f1[3]*f1[3])
                     + (f2[0]*f2[0]+f2[1]*f2[1]+f2[2]*f2[2]+f2[3]*f2[3])
                     + (f3[0]*f3[0]+f3[1]*f3[1]+f3[2]*f3[2]+f3[3]*f3[3]);
            s  += __shfl_xor(s, 16);  s  += __shfl_xor(s, 32);
            s2 += __shfl_xor(s2, 16); s2 += __shfl_xor(s2, 32);
            float mean = s * 0.015625f;
            float var  = s2 * 0.015625f - mean * mean;
            float rs   = rsqrtf(var + 1e-6f);
            float mrs  = mean * rs;
            f32x4 g0 = *(const f32x4*)(ln1g + quad * 8);
            f32x4 g1 = *(const f32x4*)(ln1g + quad * 8 + 4);
            f32x4 g2 = *(const f32x4*)(ln1g + 32 + quad * 8);
            f32x4 g3 = *(const f32x4*)(ln1g + 32 + quad * 8 + 4);
            f32x4 c0 = *(const f32x4*)(ln1b + quad * 8);
            f32x4 c1 = *(const f32x4*)(ln1b + quad * 8 + 4);
            f32x4 c2 = *(const f32x4*)(ln1b + 32 + quad * 8);
            f32x4 c3 = *(const f32x4*)(ln1b + 32 + quad * 8 + 4);
            uint4_t ra, rb;
#define LNP(va,vb,ga,gb,ca,cb) h2u(pkrtz(((va)*rs - mrs)*(ga) + (ca), ((vb)*rs - mrs)*(gb) + (cb)))
            ra[0] = LNP(f0[0],f0[1],g0[0],g0[1],c0[0],c0[1]);
            ra[1] = LNP(f0[2],f0[3],g0[2],g0[3],c0[2],c0[3]);
            ra[2] = LNP(f1[0],f1[1],g1[0],g1[1],c1[0],c1[1]);
            ra[3] = LNP(f1[2],f1[3],g1[2],g1[3],c1[2],c1[3]);
            rb[0] = LNP(f2[0],f2[1],g2[0],g2[1],c2[0],c2[1]);
            rb[1] = LNP(f2[2],f2[3],g2[2],g2[3],c2[2],c2[3]);
            rb[2] = LNP(f3[0],f3[1],g3[0],g3[1],c3[0],c3[1]);
            rb[3] = LNP(f3[2],f3[3],g3[2],g3[3],c3[2],c3[3]);
#undef LNP
            a0 = __builtin_bit_cast(f16x8, ra);
            a1 = __builtin_bit_cast(f16x8, rb);
        }
#pragma unroll
        for (int cot = 0; cot < 8; ++cot) {
            int cob = (cot < 4) ? (cs * 64 + cot * 16) : (128 + cs * 64 + (cot - 4) * 16);
            f16x8 wlo = __builtin_bit_cast(f16x8, *(const uint4_t*)(w1t + (cob + m) * 64 + quad * 8));
            f16x8 whi = __builtin_bit_cast(f16x8, *(const uint4_t*)(w1t + (cob + m) * 64 + 32 + quad * 8));
            f32x4 acc = {0.f, 0.f, 0.f, 0.f};
            acc = __builtin_amdgcn_mfma_f32_16x16x32_f16(wlo, a0, acc, 0, 0, 0);
            acc = __builtin_amdgcn_mfma_f32_16x16x32_f16(whi, a1, acc, 0, 0, 0);
            if (pin) {
                f32x4 bv = *(const f32x4*)(b1 + cob + quad * 4);
                uint2_t pk;
                pk[0] = img ? h2u(pkrtz(acc[0] + bv[0], acc[1] + bv[1])) : 0u;
                pk[1] = img ? h2u(pkrtz(acc[2] + bv[2], acc[3] + bv[3])) : 0u;
                *(uint2_t*)&uh[p * UST + cot * 16 + quad * 4] = pk;
            }
        }
    }
    __syncthreads();

    // ---- phase 2: dw3x3 + gate, packed fp16 ----
    const int y = lane >> 3, xx = lane & 7;
    const int cq = wave;
    const int gc0 = cs * 64 + cq * 16;
    const long gpx = ((long)(b * 256 + ty * 8 + y) * 256) + tx * 8 + xx;

    h2 A1[8], A2[8];
#pragma unroll
    for (int j = 0; j < 8; ++j) {
        A1[j] = u2h(0u);
        A2[j] = u2h(0u);
    }
#pragma unroll
    for (int dy = 0; dy < 3; ++dy)
#pragma unroll
    for (int dx = 0; dx < 3; ++dx) {
        int h = (y + dy) * 10 + (xx + dx);
        const uint4_t* u1p = (const uint4_t*)&uh[h * UST + cq * 16];
        const uint4_t* u2p = (const uint4_t*)&uh[h * UST + 64 + cq * 16];
        uint4_t u1l = u1p[0], u1h = u1p[1];
        uint4_t u2l = u2p[0], u2hv = u2p[1];
        const uint4_t* wp = (const uint4_t*)(dwh + (dy * 3 + dx) * 256 + gc0);
        const uint4_t* vp = (const uint4_t*)(dwh + (dy * 3 + dx) * 256 + 128 + gc0);
        uint4_t w1l = wp[0], w1h = wp[1];
        uint4_t w2l = vp[0], w2h = vp[1];
#pragma unroll
        for (int j = 0; j < 4; ++j) {
            A1[j]     += u2h(u1l[j])  * u2h(w1l[j]);
            A1[j + 4] += u2h(u1h[j])  * u2h(w1h[j]);
            A2[j]     += u2h(u2l[j])  * u2h(w2l[j]);
            A2[j + 4] += u2h(u2hv[j]) * u2h(w2h[j]);
        }
    }
    const uint4_t* bp1 = (const uint4_t*)(dbh + gc0);
    const uint4_t* bp2 = (const uint4_t*)(dbh + 128 + gc0);
    uint4_t b1l = bp1[0], b1h = bp1[1];
    uint4_t b2l = bp2[0], b2h = bp2[1];
    uint4_t s0, s1;
#pragma unroll
    for (int j = 0; j < 4; ++j) {
        h2 t0 = (A1[j]     + u2h(b1l[j])) * (A2[j]     + u2h(b2l[j]));
        h2 t1 = (A1[j + 4] + u2h(b1h[j])) * (A2[j + 4] + u2h(b2h[j]));
        s0[j] = h2u(t0);
        s1[j] = h2u(t1);
    }
    *(uint4_t*)(t + gpx * 128 + gc0)     = s0;
    *(uint4_t*)(t + gpx * 128 + gc0 + 8) = s1;
}

// ---------- K_R: GAP over t ----------
__global__ __launch_bounds__(256) void k_red(
    const short* __restrict__ t, float* __restrict__ gpart)
{
    __shared__ float red[256][2];
    const int blk = blockIdx.x;
    const int b  = blk >> 7;
    const int sb = blk & 127;
    const int tid = threadIdx.x;
    const int lane = tid & 63, wave = tid >> 6;
    const short* tb = t + ((long)(b * 65536 + sb * 512)) * 128;
    float s0 = 0.f, s1 = 0.f;
#pragma unroll 4
    for (int it = 0; it < 128; ++it) {
        int p = it * 4 + wave;
        unsigned u = *(const unsigned*)(tb + (long)p * 128 + lane * 2);
        h2 v = u2h(u);
        s0 += (float)v[0];
        s1 += (float)v[1];
    }
    red[tid][0] = s0; red[tid][1] = s1;
    __syncthreads();
    if (tid < 64) {
        float r0 = red[tid][0] + red[tid + 64][0] + red[tid + 128][0] + red[tid + 192][0];
        float r1 = red[tid][1] + red[tid + 64][1] + red[tid + 128][1] + red[tid + 192][1];
        f32x2 rv = {r0, r1};
        *(f32x2*)(gpart + (long)blk * 128 + tid * 2) = rv;
    }
}

// ---------- K_S: final GAP + SCA ----------
__global__ __launch_bounds__(1024) void k_sca2(
    const float* __restrict__ gpart, const float* __restrict__ scaw,
    const float* __restrict__ scab, float* __restrict__ watt)
{
    __shared__ float gl[1024];
    const int tid = threadIdx.x;
    const int b = tid >> 7, c = tid & 127;
    float s = 0.f;
#pragma unroll 8
    for (int i = 0; i < 128; ++i) s += gpart[(long)(b * 128 + i) * 128 + c];
    gl[tid] = s * (1.0f / 65536.0f);
    __syncthreads();
    float acc = scab[c];
    const float* g0 = gl + b * 128;
#pragma unroll 8
    for (int ci = 0; ci < 128; ++ci) acc += g0[ci] * scaw[ci * 128 + c];
    watt[tid] = acc;
}

// ---------- K_B ----------
#define XLST 72
#define ZTST 136
__global__ __launch_bounds__(256) void k_b(
    const short* __restrict__ t, const float* __restrict__ watt,
    const short* __restrict__ w2t, const float* __restrict__ b2,
    const float* __restrict__ x, const float* __restrict__ beta,
    const float* __restrict__ ln2g, const float* __restrict__ ln2b,
    const short* __restrict__ w3t, const float* __restrict__ b3,
    const short* __restrict__ w4t, const float* __restrict__ b4,
    const float* __restrict__ gamma, float* __restrict__ out)
{
    __shared__ short xl[4][16 * XLST];
    __shared__ short zt[4][16 * ZTST];
    const int lane = threadIdx.x & 63;
    const int wave = threadIdx.x >> 6;
    const int m = lane & 15, quad = lane >> 4;
    const long px0 = (long)blockIdx.x * 64 + wave * 16;
    const int b = (int)(px0 >> 16);
    const float* wa = watt + b * 128;

    const short* tr = t + (px0 + m) * 128;
    f16x8 bfr[4];
#pragma unroll
    for (int kh = 0; kh < 4; ++kh) {
        uint4_t tvv = *(const uint4_t*)(tr + kh * 32 + quad * 8);
        f32x4 w0  = *(const f32x4*)(wa + kh * 32 + quad * 8);
        f32x4 w1v = *(const f32x4*)(wa + kh * 32 + quad * 8 + 4);
        uint4_t o;
        o[0] = h2u(u2h(tvv[0]) * pkrtz(w0[0],  w0[1]));
        o[1] = h2u(u2h(tvv[1]) * pkrtz(w0[2],  w0[3]));
        o[2] = h2u(u2h(tvv[2]) * pkrtz(w1v[0], w1v[1]));
        o[3] = h2u(u2h(tvv[3]) * pkrtz(w1v[2], w1v[3]));
        bfr[kh] = __builtin_bit_cast(f16x8, o);
    }
    f32x4 acc2[4];
#pragma unroll
    for (int nt = 0; nt < 4; ++nt) { f32x4 z = {0.f,0.f,0.f,0.f}; acc2[nt] = z; }
#pragma unroll
    for (int nt = 0; nt < 4; ++nt)
#pragma unroll
        for (int kh = 0; kh < 4; ++kh) {
            f16x8 aw = __builtin_bit_cast(f16x8,
                *(const uint4_t*)(w2t + (nt * 16 + m) * 128 + kh * 32 + quad * 8));
            acc2[nt] = __builtin_amdgcn_mfma_f32_16x16x32_f16(aw, bfr[kh], acc2[nt], 0, 0, 0);
        }
    float x1v[4][4];
#pragma unroll
    for (int nt = 0; nt < 4; ++nt) {
        int cob = nt * 16 + quad * 4;
        f32x4 xv = *(const f32x4*)(x + (px0 + m) * 64 + cob);
        f32x4 bb = *(const f32x4*)(b2 + cob);
        f32x4 be = *(const f32x4*)(beta + cob);
#pragma unroll
        for (int r = 0; r < 4; ++r)
            x1v[nt][r] = xv[r] + (acc2[nt][r] + bb[r]) * be[r];
    }
    float s = 0.f, s2 = 0.f;
#pragma unroll
    for (int nt = 0; nt < 4; ++nt)
#pragma unroll
        for (int r = 0; r < 4; ++r) { s += x1v[nt][r]; s2 += x1v[nt][r] * x1v[nt][r]; }
    s  += __shfl_xor(s, 16);  s  += __shfl_xor(s, 32);
    s2 += __shfl_xor(s2, 16); s2 += __shfl_xor(s2, 32);
    float mean = s * 0.015625f;
    float var  = s2 * 0.015625f - mean * mean;
    float rs   = rsqrtf(var + 1e-6f);
    float mrs  = mean * rs;
#pragma unroll
    for (int nt = 0; nt < 4; ++nt) {
        int cob = nt * 16 + quad * 4;
        f32x4 gg = *(const f32x4*)(ln2g + cob);
        f32x4 cc = *(const f32x4*)(ln2b + cob);
        float v0 = (x1v[nt][0] * rs - mrs) * gg[0] + cc[0];
        float v1 = (x1v[nt][1] * rs - mrs) * gg[1] + cc[1];
        float v2 = (x1v[nt][2] * rs - mrs) * gg[2] + cc[2];
        float v3 = (x1v[nt][3] * rs - mrs) * gg[3] + cc[3];
        uint2_t pk;
        pk[0] = h2u(pkrtz(v0, v1));
        pk[1] = h2u(pkrtz(v2, v3));
        *(uint2_t*)&xl[wave][m * XLST + cob] = pk;
    }
    __syncthreads();
    f16x8 xb0 = __builtin_bit_cast(f16x8, *(const uint4_t*)&xl[wave][m * XLST + quad * 8]);
    f16x8 xb1 = __builtin_bit_cast(f16x8, *(const uint4_t*)&xl[wave][m * XLST + 32 + quad * 8]);
#pragma unroll
    for (int pg = 0; pg < 8; ++pg) {
        f32x4 aA = {0.f,0.f,0.f,0.f}, aB = {0.f,0.f,0.f,0.f};
        f16x8 w3a0 = __builtin_bit_cast(f16x8, *(const uint4_t*)(w3t + (pg * 16 + m) * 64 + quad * 8));
        f16x8 w3a1 = __builtin_bit_cast(f16x8, *(const uint4_t*)(w3t + (pg * 16 + m) * 64 + 32 + quad * 8));
        f16x8 w3b0 = __builtin_bit_cast(f16x8, *(const uint4_t*)(w3t + (128 + pg * 16 + m) * 64 + quad * 8));
        f16x8 w3b1 = __builtin_bit_cast(f16x8, *(const uint4_t*)(w3t + (128 + pg * 16 + m) * 64 + 32 + quad * 8));
        aA = __builtin_amdgcn_mfma_f32_16x16x32_f16(w3a0, xb0, aA, 0, 0, 0);
        aA = __builtin_amdgcn_mfma_f32_16x16x32_f16(w3a1, xb1, aA, 0, 0, 0);
        aB = __builtin_amdgcn_mfma_f32_16x16x32_f16(w3b0, xb0, aB, 0, 0, 0);
        aB = __builtin_amdgcn_mfma_f32_16x16x32_f16(w3b1, xb1, aB, 0, 0, 0);
        int cb = pg * 16 + quad * 4;
        f32x4 bA = *(const f32x4*)(b3 + cb);
        f32x4 bB = *(const f32x4*)(b3 + 128 + cb);
        float p0 = (aA[0] + bA[0]) * (aB[0] + bB[0]);
        float p1 = (aA[1] + bA[1]) * (aB[1] + bB[1]);
        float p2 = (aA[2] + bA[2]) * (aB[2] + bB[2]);
        float p3 = (aA[3] + bA[3]) * (aB[3] + bB[3]);
        uint2_t pk;
        pk[0] = h2u(pkrtz(p0, p1));
        pk[1] = h2u(pkrtz(p2, p3));
        *(uint2_t*)&zt[wave][m * ZTST + cb] = pk;
    }
    __syncthreads();
    f16x8 zb[4];
#pragma unroll
    for (int kh = 0; kh < 4; ++kh)
        zb[kh] = __builtin_bit_cast(f16x8, *(const uint4_t*)&zt[wave][m * ZTST + kh * 32 + quad * 8]);
    f32x4 acc4[4];
#pragma unroll
    for (int nt = 0; nt < 4; ++nt) { f32x4 z = {0.f,0.f,0.f,0.f}; acc4[nt] = z; }
#pragma unroll
    for (int nt = 0; nt < 4; ++nt)
#pragma unroll
        for (int kh = 0; kh < 4; ++kh) {
            f16x8 aw = __builtin_bit_cast(f16x8,
                *(const uint4_t*)(w4t + (nt * 16 + m) * 128 + kh * 32 + quad * 8));
            acc4[nt] = __builtin_amdgcn_mfma_f32_16x16x32_f16(aw, zb[kh], acc4[nt], 0, 0, 0);
        }
#pragma unroll
    for (int nt = 0; nt < 4; ++nt) {
        int cob = nt * 16 + quad * 4;
        f32x4 bb = *(const f32x4*)(b4 + cob);
        f32x4 gm = *(const f32x4*)(gamma + cob);
        f32x4 o;
#pragma unroll
        for (int r = 0; r < 4; ++r)
            o[r] = x1v[nt][r] + (acc4[nt][r] + bb[r]) * gm[r];
        *(f32x4*)(out + (px0 + m) * 64 + cob) = o;
    }
}

// ---------- launch ----------
extern "C" void kernel_launch(void* const* d_in, const int* in_sizes, int n_in,
                              void* d_out, int out_size, void* d_ws, size_t ws_size,
                              hipStream_t stream) {
    (void)in_sizes; (void)n_in; (void)out_size; (void)ws_size;
    const float* x    = (const float*)d_in[0];
    const float* ln1g = (const float*)d_in[1];
    const float* ln1b = (const float*)d_in[2];
    const float* pw1w = (const float*)d_in[3];
    const float* pw1b = (const float*)d_in[4];
    const float* dww  = (const float*)d_in[5];
    const float* dwb  = (const float*)d_in[6];
    const float* scaw = (const float*)d_in[7];
    const float* scab = (const float*)d_in[8];
    const float* pw2w = (const float*)d_in[9];
    const float* pw2b = (const float*)d_in[10];
    const float* beta = (const float*)d_in[11];
    const float* ln2g = (const float*)d_in[12];
    const float* ln2b = (const float*)d_in[13];
    const float* pw3w = (const float*)d_in[14];
    const float* pw3b = (const float*)d_in[15];
    const float* pw4w = (const float*)d_in[16];
    const float* pw4b = (const float*)d_in[17];
    const float* gamma= (const float*)d_in[18];

    char* ws = (char*)d_ws;
    short* w1t = (short*)(ws + OFF_W1T);
    short* w2t = (short*)(ws + OFF_W2T);
    short* w3t = (short*)(ws + OFF_W3T);
    short* w4t = (short*)(ws + OFF_W4T);
    short* dwh = (short*)(ws + OFF_DWH);
    short* dbh = (short*)(ws + OFF_DBH);
    float* watt = (float*)(ws + OFF_WATT);
    float* gpart = (float*)(ws + OFF_GPART);
    short* t   = (short*)(ws + OFF_T);
    float* out = (float*)d_out;

    k_prep<<<64, 256, 0, stream>>>(pw1w, pw2w, pw3w, pw4w, dww, dwb,
                                   w1t, w2t, w3t, w4t, dwh, dbh);
    k_a<<<16384, 256, 0, stream>>>(x, ln1g, ln1b, w1t, pw1b, dwh, dbh, t);
    k_red<<<1024, 256, 0, stream>>>(t, gpart);
    k_sca2<<<1, 1024, 0, stream>>>(gpart, scaw, scab, watt);
    k_b<<<8192, 256, 0, stream>>>(t, watt, w2t, pw2b, x, beta, ln2g, ln2b,
                                  w3t, pw3b, w4t, pw4b, gamma, out);
}

// Round 3
// 860.932 us; speedup vs baseline: 1.0883x; 1.0048x over previous
//
#include <hip/hip_runtime.h>

// ---------- types / helpers ----------
typedef __attribute__((ext_vector_type(8))) _Float16 f16x8;
typedef __attribute__((ext_vector_type(2))) _Float16 h2;
typedef __attribute__((ext_vector_type(4))) float f32x4;
typedef __attribute__((ext_vector_type(2))) float f32x2;
typedef __attribute__((ext_vector_type(4))) unsigned uint4_t;
typedef __attribute__((ext_vector_type(2))) unsigned uint2_t;

__device__ __forceinline__ h2 pkrtz(float a, float b) {
    return __builtin_bit_cast(h2, __builtin_amdgcn_cvt_pkrtz(a, b));   // v_cvt_pkrtz_f16_f32
}
__device__ __forceinline__ unsigned h2u(h2 v) { return __builtin_bit_cast(unsigned, v); }
__device__ __forceinline__ h2 u2h(unsigned u) { return __builtin_bit_cast(h2, u); }
__device__ __forceinline__ short f2h(float f) { return __builtin_bit_cast(short, (_Float16)f); }

// ws layout (bytes)
#define OFF_W1T 0L            // 32768
#define OFF_W2T 32768L        // 16384
#define OFF_W3T 49152L        // 32768
#define OFF_W4T 81920L        // 16384
#define OFF_DWH 98304L        // 4608
#define OFF_DBH 102912L       // 512
#define OFF_WATT 103424L      // 4096
#define OFF_GPART 107520L     // 2048*128*4 = 1048576
#define OFF_T 1156096L        // 524288*128*2 = 134217728

// ---------- K0: weight transpose + fp16 cast ----------
__global__ __launch_bounds__(256) void k_prep(
    const float* __restrict__ w1, const float* __restrict__ w2,
    const float* __restrict__ w3, const float* __restrict__ w4,
    const float* __restrict__ dww, const float* __restrict__ dwb,
    short* __restrict__ w1t, short* __restrict__ w2t,
    short* __restrict__ w3t, short* __restrict__ w4t,
    short* __restrict__ dwh, short* __restrict__ dbh)
{
    int id = blockIdx.x * 256 + threadIdx.x;
    if (id < 64 * 256) {
        int ci = id >> 8, co = id & 255;
        w1t[co * 64 + ci] = f2h(w1[id]);
        w3t[co * 64 + ci] = f2h(w3[id]);
    }
    if (id < 128 * 64) {
        int ci = id >> 6, co = id & 63;
        w2t[co * 128 + ci] = f2h(w2[id]);
        w4t[co * 128 + ci] = f2h(w4[id]);
    }
    if (id < 9 * 256) dwh[id] = f2h(dww[id]);
    if (id < 256)     dbh[id] = f2h(dwb[id]);
}

// ---------- K_A: LN1 + pw1(MFMA) + dw3x3 + gate ----------
#define UST 136
__global__ __launch_bounds__(256) void k_a(
    const float* __restrict__ x, const float* __restrict__ ln1g, const float* __restrict__ ln1b,
    const short* __restrict__ w1t, const float* __restrict__ b1,
    const short* __restrict__ dwh, const short* __restrict__ dbh,
    short* __restrict__ t)
{
    __shared__ short uh[100 * UST];
    const int blk = blockIdx.x;
    const int cs  = blk & 1;
    const int txy = blk >> 1;
    const int tx  = txy & 31;
    const int ty  = (txy >> 5) & 31;
    const int b   = txy >> 10;
    const int tid = threadIdx.x;
    const int lane = tid & 63;
    const int wave = tid >> 6;
    const int m    = lane & 15;
    const int quad = lane >> 4;

    // ---- phase 1: two pixel-slots per wave (pA = wave*16+m, pB = pA+64),
    //      both global loads issued up-front so the second latency hides
    //      under the first slot's LN + MFMA work.
    const int pA = wave * 16 + m;
    const int pB = pA + 64;
    const int hyA = (pA * 205) >> 11, hxA = pA - hyA * 10;
    const int hyB = (pB * 205) >> 11, hxB = pB - hyB * 10;
    const int gyA = ty * 8 + hyA - 1, gxA = tx * 8 + hxA - 1;
    const int gyB = ty * 8 + hyB - 1, gxB = tx * 8 + hxB - 1;
    const bool imgA = gyA >= 0 && gyA < 256 && gxA >= 0 && gxA < 256;  // pA<100 always
    const bool imgB = (pB < 100) && gyB >= 0 && gyB < 256 && gxB >= 0 && gxB < 256;
    const bool aliveB = (wave < 3);   // wave3's B slot (p>=112) is fully dead

    f32x4 fA[4], fB[4];
#pragma unroll
    for (int i = 0; i < 4; ++i) {
        fA[i] = (f32x4){0.f,0.f,0.f,0.f};
        fB[i] = (f32x4){0.f,0.f,0.f,0.f};
    }
    if (imgA) {
        const float* xr = x + ((long)((b * 256 + gyA) * 256 + gxA)) * 64 + quad * 8;
        fA[0] = *(const f32x4*)(xr);      fA[1] = *(const f32x4*)(xr + 4);
        fA[2] = *(const f32x4*)(xr + 32); fA[3] = *(const f32x4*)(xr + 36);
    }
    if (imgB) {
        const float* xr = x + ((long)((b * 256 + gyB) * 256 + gxB)) * 64 + quad * 8;
        fB[0] = *(const f32x4*)(xr);      fB[1] = *(const f32x4*)(xr + 4);
        fB[2] = *(const f32x4*)(xr + 32); fB[3] = *(const f32x4*)(xr + 36);
    }

    f16x8 a0A = {0,0,0,0,0,0,0,0}, a1A = {0,0,0,0,0,0,0,0};
    f16x8 a0B = {0,0,0,0,0,0,0,0}, a1B = {0,0,0,0,0,0,0,0};

    // LN slot A (quad-partners share img, so shuffles are safe)
    if (imgA) {
        float s  = 0.f, s2 = 0.f;
#pragma unroll
        for (int i = 0; i < 4; ++i)
#pragma unroll
            for (int r = 0; r < 4; ++r) { s += fA[i][r]; s2 += fA[i][r] * fA[i][r]; }
        s  += __shfl_xor(s, 16);  s  += __shfl_xor(s, 32);
        s2 += __shfl_xor(s2, 16); s2 += __shfl_xor(s2, 32);
        float mean = s * 0.015625f;
        float var  = s2 * 0.015625f - mean * mean;
        float rs   = rsqrtf(var + 1e-6f);
        float mrs  = mean * rs;
        f32x4 g0 = *(const f32x4*)(ln1g + quad * 8);
        f32x4 g1 = *(const f32x4*)(ln1g + quad * 8 + 4);
        f32x4 g2 = *(const f32x4*)(ln1g + 32 + quad * 8);
        f32x4 g3 = *(const f32x4*)(ln1g + 32 + quad * 8 + 4);
        f32x4 c0 = *(const f32x4*)(ln1b + quad * 8);
        f32x4 c1 = *(const f32x4*)(ln1b + quad * 8 + 4);
        f32x4 c2 = *(const f32x4*)(ln1b + 32 + quad * 8);
        f32x4 c3 = *(const f32x4*)(ln1b + 32 + quad * 8 + 4);
        uint4_t ra, rb;
#define LNP(va,vb,ga,gb,ca,cb) h2u(pkrtz(((va)*rs - mrs)*(ga) + (ca), ((vb)*rs - mrs)*(gb) + (cb)))
        ra[0] = LNP(fA[0][0],fA[0][1],g0[0],g0[1],c0[0],c0[1]);
        ra[1] = LNP(fA[0][2],fA[0][3],g0[2],g0[3],c0[2],c0[3]);
        ra[2] = LNP(fA[1][0],fA[1][1],g1[0],g1[1],c1[0],c1[1]);
        ra[3] = LNP(fA[1][2],fA[1][3],g1[2],g1[3],c1[2],c1[3]);
        rb[0] = LNP(fA[2][0],fA[2][1],g2[0],g2[1],c2[0],c2[1]);
        rb[1] = LNP(fA[2][2],fA[2][3],g2[2],g2[3],c2[2],c2[3]);
        rb[2] = LNP(fA[3][0],fA[3][1],g3[0],g3[1],c3[0],c3[1]);
        rb[3] = LNP(fA[3][2],fA[3][3],g3[2],g3[3],c3[2],c3[3]);
        a0A = __builtin_bit_cast(f16x8, ra);
        a1A = __builtin_bit_cast(f16x8, rb);
    }
    // LN slot B
    if (imgB) {
        float s  = 0.f, s2 = 0.f;
#pragma unroll
        for (int i = 0; i < 4; ++i)
#pragma unroll
            for (int r = 0; r < 4; ++r) { s += fB[i][r]; s2 += fB[i][r] * fB[i][r]; }
        s  += __shfl_xor(s, 16);  s  += __shfl_xor(s, 32);
        s2 += __shfl_xor(s2, 16); s2 += __shfl_xor(s2, 32);
        float mean = s * 0.015625f;
        float var  = s2 * 0.015625f - mean * mean;
        float rs   = rsqrtf(var + 1e-6f);
        float mrs  = mean * rs;
        f32x4 g0 = *(const f32x4*)(ln1g + quad * 8);
        f32x4 g1 = *(const f32x4*)(ln1g + quad * 8 + 4);
        f32x4 g2 = *(const f32x4*)(ln1g + 32 + quad * 8);
        f32x4 g3 = *(const f32x4*)(ln1g + 32 + quad * 8 + 4);
        f32x4 c0 = *(const f32x4*)(ln1b + quad * 8);
        f32x4 c1 = *(const f32x4*)(ln1b + quad * 8 + 4);
        f32x4 c2 = *(const f32x4*)(ln1b + 32 + quad * 8);
        f32x4 c3 = *(const f32x4*)(ln1b + 32 + quad * 8 + 4);
        uint4_t ra, rb;
        ra[0] = LNP(fB[0][0],fB[0][1],g0[0],g0[1],c0[0],c0[1]);
        ra[1] = LNP(fB[0][2],fB[0][3],g0[2],g0[3],c0[2],c0[3]);
        ra[2] = LNP(fB[1][0],fB[1][1],g1[0],g1[1],c1[0],c1[1]);
        ra[3] = LNP(fB[1][2],fB[1][3],g1[2],g1[3],c1[2],c1[3]);
        rb[0] = LNP(fB[2][0],fB[2][1],g2[0],g2[1],c2[0],c2[1]);
        rb[1] = LNP(fB[2][2],fB[2][3],g2[2],g2[3],c2[2],c2[3]);
        rb[2] = LNP(fB[3][0],fB[3][1],g3[0],g3[1],c3[0],c3[1]);
        rb[3] = LNP(fB[3][2],fB[3][3],g3[2],g3[3],c3[2],c3[3]);
#undef LNP
        a0B = __builtin_bit_cast(f16x8, ra);
        a1B = __builtin_bit_cast(f16x8, rb);
    }

    // MFMA: each w1t/b1 fragment loaded once, feeds both slots
#pragma unroll
    for (int cot = 0; cot < 8; ++cot) {
        const int cob = (cot < 4) ? (cs * 64 + cot * 16) : (128 + cs * 64 + (cot - 4) * 16);
        const f16x8 wlo = __builtin_bit_cast(f16x8, *(const uint4_t*)(w1t + (cob + m) * 64 + quad * 8));
        const f16x8 whi = __builtin_bit_cast(f16x8, *(const uint4_t*)(w1t + (cob + m) * 64 + 32 + quad * 8));
        const f32x4 bv = *(const f32x4*)(b1 + cob + quad * 4);
        {
            f32x4 acc = {0.f,0.f,0.f,0.f};
            acc = __builtin_amdgcn_mfma_f32_16x16x32_f16(wlo, a0A, acc, 0, 0, 0);
            acc = __builtin_amdgcn_mfma_f32_16x16x32_f16(whi, a1A, acc, 0, 0, 0);
            uint2_t pk;
            pk[0] = imgA ? h2u(pkrtz(acc[0] + bv[0], acc[1] + bv[1])) : 0u;
            pk[1] = imgA ? h2u(pkrtz(acc[2] + bv[2], acc[3] + bv[3])) : 0u;
            *(uint2_t*)&uh[pA * UST + cot * 16 + quad * 4] = pk;
        }
        if (aliveB) {
            f32x4 acc = {0.f,0.f,0.f,0.f};
            acc = __builtin_amdgcn_mfma_f32_16x16x32_f16(wlo, a0B, acc, 0, 0, 0);
            acc = __builtin_amdgcn_mfma_f32_16x16x32_f16(whi, a1B, acc, 0, 0, 0);
            if (pB < 100) {
                uint2_t pk;
                pk[0] = imgB ? h2u(pkrtz(acc[0] + bv[0], acc[1] + bv[1])) : 0u;
                pk[1] = imgB ? h2u(pkrtz(acc[2] + bv[2], acc[3] + bv[3])) : 0u;
                *(uint2_t*)&uh[pB * UST + cot * 16 + quad * 4] = pk;
            }
        }
    }
    __syncthreads();

    // ---- phase 2: dw3x3 + gate, packed fp16 ----
    const int y = lane >> 3, xx = lane & 7;
    const int cq = wave;
    const int gc0 = cs * 64 + cq * 16;
    const long gpx = ((long)(b * 256 + ty * 8 + y) * 256) + tx * 8 + xx;

    h2 A1[8], A2[8];
#pragma unroll
    for (int j = 0; j < 8; ++j) {
        A1[j] = u2h(0u);
        A2[j] = u2h(0u);
    }
#pragma unroll
    for (int dy = 0; dy < 3; ++dy)
#pragma unroll
    for (int dx = 0; dx < 3; ++dx) {
        int h = (y + dy) * 10 + (xx + dx);
        const uint4_t* u1p = (const uint4_t*)&uh[h * UST + cq * 16];
        const uint4_t* u2p = (const uint4_t*)&uh[h * UST + 64 + cq * 16];
        uint4_t u1l = u1p[0], u1h = u1p[1];
        uint4_t u2l = u2p[0], u2hv = u2p[1];
        const uint4_t* wp = (const uint4_t*)(dwh + (dy * 3 + dx) * 256 + gc0);
        const uint4_t* vp = (const uint4_t*)(dwh + (dy * 3 + dx) * 256 + 128 + gc0);
        uint4_t w1l = wp[0], w1h = wp[1];
        uint4_t w2l = vp[0], w2h = vp[1];
#pragma unroll
        for (int j = 0; j < 4; ++j) {
            A1[j]     += u2h(u1l[j])  * u2h(w1l[j]);
            A1[j + 4] += u2h(u1h[j])  * u2h(w1h[j]);
            A2[j]     += u2h(u2l[j])  * u2h(w2l[j]);
            A2[j + 4] += u2h(u2hv[j]) * u2h(w2h[j]);
        }
    }
    const uint4_t* bp1 = (const uint4_t*)(dbh + gc0);
    const uint4_t* bp2 = (const uint4_t*)(dbh + 128 + gc0);
    uint4_t b1l = bp1[0], b1h = bp1[1];
    uint4_t b2l = bp2[0], b2h = bp2[1];
    uint4_t s0, s1;
#pragma unroll
    for (int j = 0; j < 4; ++j) {
        h2 t0 = (A1[j]     + u2h(b1l[j])) * (A2[j]     + u2h(b2l[j]));
        h2 t1 = (A1[j + 4] + u2h(b1h[j])) * (A2[j + 4] + u2h(b2h[j]));
        s0[j] = h2u(t0);
        s1[j] = h2u(t1);
    }
    *(uint4_t*)(t + gpx * 128 + gc0)     = s0;
    *(uint4_t*)(t + gpx * 128 + gc0 + 8) = s1;
}

// ---------- K_R: GAP over t (b128 loads, 2048 blocks) ----------
__global__ __launch_bounds__(256) void k_red(
    const short* __restrict__ t, float* __restrict__ gpart)
{
    __shared__ float red[16][16][8];   // [pr][cg][j]  8 KB
    const int blk = blockIdx.x;        // 2048 = 8 batch x 256 slices
    const int tid = threadIdx.x;
    const int cg = tid & 15;
    const int pr = tid >> 4;
    const short* tb = t + (long)blk * 256 * 128 + cg * 8;
    float a0=0,a1=0,a2=0,a3=0,a4=0,a5=0,a6=0,a7=0;
#pragma unroll 4
    for (int it = 0; it < 16; ++it) {
        uint4_t u = *(const uint4_t*)(tb + (long)(it * 16 + pr) * 128);
        h2 v0=u2h(u[0]), v1=u2h(u[1]), v2=u2h(u[2]), v3=u2h(u[3]);
        a0 += (float)v0[0]; a1 += (float)v0[1]; a2 += (float)v1[0]; a3 += (float)v1[1];
        a4 += (float)v2[0]; a5 += (float)v2[1]; a6 += (float)v3[0]; a7 += (float)v3[1];
    }
    red[pr][cg][0]=a0; red[pr][cg][1]=a1; red[pr][cg][2]=a2; red[pr][cg][3]=a3;
    red[pr][cg][4]=a4; red[pr][cg][5]=a5; red[pr][cg][6]=a6; red[pr][cg][7]=a7;
    __syncthreads();
    if (tid < 128) {
        int g = tid >> 3, j = tid & 7;
        float s = 0.f;
#pragma unroll
        for (int r = 0; r < 16; ++r) s += red[r][g][j];
        gpart[(long)blk * 128 + tid] = s;
    }
}

// ---------- K_S: final GAP + SCA (one block per batch) ----------
__global__ __launch_bounds__(256) void k_sca2(
    const float* __restrict__ gpart, const float* __restrict__ scaw,
    const float* __restrict__ scab, float* __restrict__ watt)
{
    __shared__ float gl[256];
    __shared__ float gn[128];
    const int b = blockIdx.x;
    const int tid = threadIdx.x;
    const int c = tid & 127, half = tid >> 7;
    float s = 0.f;
    const float* gp = gpart + (long)b * 256 * 128 + c;
    for (int i = half; i < 256; i += 2) s += gp[(long)i * 128];
    gl[half * 128 + c] = s;
    __syncthreads();
    if (tid < 128) gn[c] = (gl[c] + gl[128 + c]) * (1.0f / 65536.0f);
    __syncthreads();
    if (tid < 128) {
        float acc = scab[c];
        for (int ci = 0; ci < 128; ++ci) acc += gn[ci] * scaw[ci * 128 + c];
        watt[b * 128 + c] = acc;
    }
}

// ---------- K_B ----------
#define XLST 72
#define ZTST 136
__global__ __launch_bounds__(256) void k_b(
    const short* __restrict__ t, const float* __restrict__ watt,
    const short* __restrict__ w2t, const float* __restrict__ b2,
    const float* __restrict__ x, const float* __restrict__ beta,
    const float* __restrict__ ln2g, const float* __restrict__ ln2b,
    const short* __restrict__ w3t, const float* __restrict__ b3,
    const short* __restrict__ w4t, const float* __restrict__ b4,
    const float* __restrict__ gamma, float* __restrict__ out)
{
    __shared__ short xl[4][16 * XLST];
    __shared__ short zt[4][16 * ZTST];
    const int lane = threadIdx.x & 63;
    const int wave = threadIdx.x >> 6;
    const int m = lane & 15, quad = lane >> 4;
    const long px0 = (long)blockIdx.x * 64 + wave * 16;
    const int b = (int)(px0 >> 16);
    const float* wa = watt + b * 128;

    // issue residual x loads FIRST: latency hides under t-load + pw2 MFMA
    f32x4 xv[4];
#pragma unroll
    for (int nt = 0; nt < 4; ++nt)
        xv[nt] = *(const f32x4*)(x + (px0 + m) * 64 + nt * 16 + quad * 4);

    const short* tr = t + (px0 + m) * 128;
    f16x8 bfr[4];
#pragma unroll
    for (int kh = 0; kh < 4; ++kh) {
        uint4_t tvv = *(const uint4_t*)(tr + kh * 32 + quad * 8);
        f32x4 w0  = *(const f32x4*)(wa + kh * 32 + quad * 8);
        f32x4 w1v = *(const f32x4*)(wa + kh * 32 + quad * 8 + 4);
        uint4_t o;
        o[0] = h2u(u2h(tvv[0]) * pkrtz(w0[0],  w0[1]));
        o[1] = h2u(u2h(tvv[1]) * pkrtz(w0[2],  w0[3]));
        o[2] = h2u(u2h(tvv[2]) * pkrtz(w1v[0], w1v[1]));
        o[3] = h2u(u2h(tvv[3]) * pkrtz(w1v[2], w1v[3]));
        bfr[kh] = __builtin_bit_cast(f16x8, o);
    }
    f32x4 acc2[4];
#pragma unroll
    for (int nt = 0; nt < 4; ++nt) { f32x4 z = {0.f,0.f,0.f,0.f}; acc2[nt] = z; }
#pragma unroll
    for (int nt = 0; nt < 4; ++nt)
#pragma unroll
        for (int kh = 0; kh < 4; ++kh) {
            f16x8 aw = __builtin_bit_cast(f16x8,
                *(const uint4_t*)(w2t + (nt * 16 + m) * 128 + kh * 32 + quad * 8));
            acc2[nt] = __builtin_amdgcn_mfma_f32_16x16x32_f16(aw, bfr[kh], acc2[nt], 0, 0, 0);
        }
    float x1v[4][4];
#pragma unroll
    for (int nt = 0; nt < 4; ++nt) {
        int cob = nt * 16 + quad * 4;
        f32x4 bb = *(const f32x4*)(b2 + cob);
        f32x4 be = *(const f32x4*)(beta + cob);
#pragma unroll
        for (int r = 0; r < 4; ++r)
            x1v[nt][r] = xv[nt][r] + (acc2[nt][r] + bb[r]) * be[r];
    }
    float s = 0.f, s2 = 0.f;
#pragma unroll
    for (int nt = 0; nt < 4; ++nt)
#pragma unroll
        for (int r = 0; r < 4; ++r) { s += x1v[nt][r]; s2 += x1v[nt][r] * x1v[nt][r]; }
    s  += __shfl_xor(s, 16);  s  += __shfl_xor(s, 32);
    s2 += __shfl_xor(s2, 16); s2 += __shfl_xor(s2, 32);
    float mean = s * 0.015625f;
    float var  = s2 * 0.015625f - mean * mean;
    float rs   = rsqrtf(var + 1e-6f);
    float mrs  = mean * rs;
#pragma unroll
    for (int nt = 0; nt < 4; ++nt) {
        int cob = nt * 16 + quad * 4;
        f32x4 gg = *(const f32x4*)(ln2g + cob);
        f32x4 cc = *(const f32x4*)(ln2b + cob);
        float v0 = (x1v[nt][0] * rs - mrs) * gg[0] + cc[0];
        float v1 = (x1v[nt][1] * rs - mrs) * gg[1] + cc[1];
        float v2 = (x1v[nt][2] * rs - mrs) * gg[2] + cc[2];
        float v3 = (x1v[nt][3] * rs - mrs) * gg[3] + cc[3];
        uint2_t pk;
        pk[0] = h2u(pkrtz(v0, v1));
        pk[1] = h2u(pkrtz(v2, v3));
        *(uint2_t*)&xl[wave][m * XLST + cob] = pk;
    }
    __syncthreads();
    f16x8 xb0 = __builtin_bit_cast(f16x8, *(const uint4_t*)&xl[wave][m * XLST + quad * 8]);
    f16x8 xb1 = __builtin_bit_cast(f16x8, *(const uint4_t*)&xl[wave][m * XLST + 32 + quad * 8]);
#pragma unroll
    for (int pg = 0; pg < 8; ++pg) {
        f32x4 aA = {0.f,0.f,0.f,0.f}, aB = {0.f,0.f,0.f,0.f};
        f16x8 w3a0 = __builtin_bit_cast(f16x8, *(const uint4_t*)(w3t + (pg * 16 + m) * 64 + quad * 8));
        f16x8 w3a1 = __builtin_bit_cast(f16x8, *(const uint4_t*)(w3t + (pg * 16 + m) * 64 + 32 + quad * 8));
        f16x8 w3b0 = __builtin_bit_cast(f16x8, *(const uint4_t*)(w3t + (128 + pg * 16 + m) * 64 + quad * 8));
        f16x8 w3b1 = __builtin_bit_cast(f16x8, *(const uint4_t*)(w3t + (128 + pg * 16 + m) * 64 + 32 + quad * 8));
        aA = __builtin_amdgcn_mfma_f32_16x16x32_f16(w3a0, xb0, aA, 0, 0, 0);
        aA = __builtin_amdgcn_mfma_f32_16x16x32_f16(w3a1, xb1, aA, 0, 0, 0);
        aB = __builtin_amdgcn_mfma_f32_16x16x32_f16(w3b0, xb0, aB, 0, 0, 0);
        aB = __builtin_amdgcn_mfma_f32_16x16x32_f16(w3b1, xb1, aB, 0, 0, 0);
        int cb = pg * 16 + quad * 4;
        f32x4 bA = *(const f32x4*)(b3 + cb);
        f32x4 bB = *(const f32x4*)(b3 + 128 + cb);
        float p0 = (aA[0] + bA[0]) * (aB[0] + bB[0]);
        float p1 = (aA[1] + bA[1]) * (aB[1] + bB[1]);
        float p2 = (aA[2] + bA[2]) * (aB[2] + bB[2]);
        float p3 = (aA[3] + bA[3]) * (aB[3] + bB[3]);
        uint2_t pk;
        pk[0] = h2u(pkrtz(p0, p1));
        pk[1] = h2u(pkrtz(p2, p3));
        *(uint2_t*)&zt[wave][m * ZTST + cb] = pk;
    }
    __syncthreads();
    f16x8 zb[4];
#pragma unroll
    for (int kh = 0; kh < 4; ++kh)
        zb[kh] = __builtin_bit_cast(f16x8, *(const uint4_t*)&zt[wave][m * ZTST + kh * 32 + quad * 8]);
    f32x4 acc4[4];
#pragma unroll
    for (int nt = 0; nt < 4; ++nt) { f32x4 z = {0.f,0.f,0.f,0.f}; acc4[nt] = z; }
#pragma unroll
    for (int nt = 0; nt < 4; ++nt)
#pragma unroll
        for (int kh = 0; kh < 4; ++kh) {
            f16x8 aw = __builtin_bit_cast(f16x8,
                *(const uint4_t*)(w4t + (nt * 16 + m) * 128 + kh * 32 + quad * 8));
            acc4[nt] = __builtin_amdgcn_mfma_f32_16x16x32_f16(aw, zb[kh], acc4[nt], 0, 0, 0);
        }
#pragma unroll
    for (int nt = 0; nt < 4; ++nt) {
        int cob = nt * 16 + quad * 4;
        f32x4 bb = *(const f32x4*)(b4 + cob);
        f32x4 gm = *(const f32x4*)(gamma + cob);
        f32x4 o;
#pragma unroll
        for (int r = 0; r < 4; ++r)
            o[r] = x1v[nt][r] + (acc4[nt][r] + bb[r]) * gm[r];
        *(f32x4*)(out + (px0 + m) * 64 + cob) = o;
    }
}

// ---------- launch ----------
extern "C" void kernel_launch(void* const* d_in, const int* in_sizes, int n_in,
                              void* d_out, int out_size, void* d_ws, size_t ws_size,
                              hipStream_t stream) {
    (void)in_sizes; (void)n_in; (void)out_size; (void)ws_size;
    const float* x    = (const float*)d_in[0];
    const float* ln1g = (const float*)d_in[1];
    const float* ln1b = (const float*)d_in[2];
    const float* pw1w = (const float*)d_in[3];
    const float* pw1b = (const float*)d_in[4];
    const float* dww  = (const float*)d_in[5];
    const float* dwb  = (const float*)d_in[6];
    const float* scaw = (const float*)d_in[7];
    const float* scab = (const float*)d_in[8];
    const float* pw2w = (const float*)d_in[9];
    const float* pw2b = (const float*)d_in[10];
    const float* beta = (const float*)d_in[11];
    const float* ln2g = (const float*)d_in[12];
    const float* ln2b = (const float*)d_in[13];
    const float* pw3w = (const float*)d_in[14];
    const float* pw3b = (const float*)d_in[15];
    const float* pw4w = (const float*)d_in[16];
    const float* pw4b = (const float*)d_in[17];
    const float* gamma= (const float*)d_in[18];

    char* ws = (char*)d_ws;
    short* w1t = (short*)(ws + OFF_W1T);
    short* w2t = (short*)(ws + OFF_W2T);
    short* w3t = (short*)(ws + OFF_W3T);
    short* w4t = (short*)(ws + OFF_W4T);
    short* dwh = (short*)(ws + OFF_DWH);
    short* dbh = (short*)(ws + OFF_DBH);
    float* watt = (float*)(ws + OFF_WATT);
    float* gpart = (float*)(ws + OFF_GPART);
    short* t   = (short*)(ws + OFF_T);
    float* out = (float*)d_out;

    k_prep<<<64, 256, 0, stream>>>(pw1w, pw2w, pw3w, pw4w, dww, dwb,
                                   w1t, w2t, w3t, w4t, dwh, dbh);
    k_a<<<16384, 256, 0, stream>>>(x, ln1g, ln1b, w1t, pw1b, dwh, dbh, t);
    k_red<<<2048, 256, 0, stream>>>(t, gpart);
    k_sca2<<<8, 256, 0, stream>>>(gpart, scaw, scab, watt);
    k_b<<<8192, 256, 0, stream>>>(t, watt, w2t, pw2b, x, beta, ln2g, ln2b,
                                  w3t, pw3b, w4t, pw4b, gamma, out);
}

// Round 5
// 853.663 us; speedup vs baseline: 1.0975x; 1.0085x over previous
//
#include <hip/hip_runtime.h>

// ---------- types / helpers ----------
typedef __attribute__((ext_vector_type(8))) _Float16 f16x8;
typedef __attribute__((ext_vector_type(2))) _Float16 h2;
typedef __attribute__((ext_vector_type(4))) float f32x4;
typedef __attribute__((ext_vector_type(2))) float f32x2;
typedef __attribute__((ext_vector_type(4))) unsigned uint4_t;
typedef __attribute__((ext_vector_type(2))) unsigned uint2_t;

__device__ __forceinline__ h2 pkrtz(float a, float b) {
    return __builtin_bit_cast(h2, __builtin_amdgcn_cvt_pkrtz(a, b));   // v_cvt_pkrtz_f16_f32
}
__device__ __forceinline__ unsigned h2u(h2 v) { return __builtin_bit_cast(unsigned, v); }
__device__ __forceinline__ h2 u2h(unsigned u) { return __builtin_bit_cast(h2, u); }
__device__ __forceinline__ short f2h(float f) { return __builtin_bit_cast(short, (_Float16)f); }

// ws layout (bytes)
#define OFF_W1T 0L            // 32768
#define OFF_W2T 32768L        // 16384
#define OFF_W3T 49152L        // 32768
#define OFF_W4T 81920L        // 16384
#define OFF_DWH 98304L        // 4608
#define OFF_DBH 102912L       // 512
#define OFF_WATT 103424L      // 4096
#define OFF_GPART 107520L     // 2048*128*4 = 1048576
#define OFF_T 1156096L        // 524288*128*2 = 134217728

// ---------- K0: weight transpose + fp16 cast ----------
__global__ __launch_bounds__(256) void k_prep(
    const float* __restrict__ w1, const float* __restrict__ w2,
    const float* __restrict__ w3, const float* __restrict__ w4,
    const float* __restrict__ dww, const float* __restrict__ dwb,
    short* __restrict__ w1t, short* __restrict__ w2t,
    short* __restrict__ w3t, short* __restrict__ w4t,
    short* __restrict__ dwh, short* __restrict__ dbh)
{
    int id = blockIdx.x * 256 + threadIdx.x;
    if (id < 64 * 256) {
        int ci = id >> 8, co = id & 255;
        w1t[co * 64 + ci] = f2h(w1[id]);
        w3t[co * 64 + ci] = f2h(w3[id]);
    }
    if (id < 128 * 64) {
        int ci = id >> 6, co = id & 63;
        w2t[co * 128 + ci] = f2h(w2[id]);
        w4t[co * 128 + ci] = f2h(w4[id]);
    }
    if (id < 9 * 256) dwh[id] = f2h(dww[id]);
    if (id < 256)     dbh[id] = f2h(dwb[id]);
}

// ---------- K_A: LN1 + pw1(MFMA) + dw3x3 + gate ----------
// LDS: u tile [100 rows][128 shorts], XOR-swizzled (byte ^= (row&7)<<4) to
// keep bank access uniform at stride-128. 25600 B -> 6 blocks/CU.
__global__ __launch_bounds__(256) void k_a(
    const float* __restrict__ x, const float* __restrict__ ln1g, const float* __restrict__ ln1b,
    const short* __restrict__ w1t, const float* __restrict__ b1,
    const short* __restrict__ dwh, const short* __restrict__ dbh,
    short* __restrict__ t)
{
    __shared__ short uh[100 * 128];   // 25600 B
    const int blk = blockIdx.x;
    const int cs  = blk & 1;
    const int txy = blk >> 1;
    const int tx  = txy & 31;
    const int ty  = (txy >> 5) & 31;
    const int b   = txy >> 10;
    const int tid = threadIdx.x;
    const int lane = tid & 63;
    const int wave = tid >> 6;
    const int m    = lane & 15;
    const int quad = lane >> 4;

    // ---- phase 1: two pixel-slots per wave (pA = wave*16+m, pB = pA+64)
    const int pA = wave * 16 + m;
    const int pB = pA + 64;
    const int hyA = (pA * 205) >> 11, hxA = pA - hyA * 10;
    const int hyB = (pB * 205) >> 11, hxB = pB - hyB * 10;
    const int gyA = ty * 8 + hyA - 1, gxA = tx * 8 + hxA - 1;
    const int gyB = ty * 8 + hyB - 1, gxB = tx * 8 + hxB - 1;
    const bool imgA = gyA >= 0 && gyA < 256 && gxA >= 0 && gxA < 256;  // pA<100 always
    const bool imgB = (pB < 100) && gyB >= 0 && gyB < 256 && gxB >= 0 && gxB < 256;
    const bool aliveB = (wave < 3);   // wave3's B slot (p>=112) fully dead

    f32x4 fA[4], fB[4];
#pragma unroll
    for (int i = 0; i < 4; ++i) {
        fA[i] = (f32x4){0.f,0.f,0.f,0.f};
        fB[i] = (f32x4){0.f,0.f,0.f,0.f};
    }
    if (imgA) {
        const float* xr = x + ((long)((b * 256 + gyA) * 256 + gxA)) * 64 + quad * 8;
        fA[0] = *(const f32x4*)(xr);      fA[1] = *(const f32x4*)(xr + 4);
        fA[2] = *(const f32x4*)(xr + 32); fA[3] = *(const f32x4*)(xr + 36);
    }
    if (imgB) {
        const float* xr = x + ((long)((b * 256 + gyB) * 256 + gxB)) * 64 + quad * 8;
        fB[0] = *(const f32x4*)(xr);      fB[1] = *(const f32x4*)(xr + 4);
        fB[2] = *(const f32x4*)(xr + 32); fB[3] = *(const f32x4*)(xr + 36);
    }

    // LN affine params loaded once, shared by both slots
    f32x4 g0 = *(const f32x4*)(ln1g + quad * 8);
    f32x4 g1 = *(const f32x4*)(ln1g + quad * 8 + 4);
    f32x4 g2 = *(const f32x4*)(ln1g + 32 + quad * 8);
    f32x4 g3 = *(const f32x4*)(ln1g + 32 + quad * 8 + 4);
    f32x4 c0 = *(const f32x4*)(ln1b + quad * 8);
    f32x4 c1 = *(const f32x4*)(ln1b + quad * 8 + 4);
    f32x4 c2 = *(const f32x4*)(ln1b + 32 + quad * 8);
    f32x4 c3 = *(const f32x4*)(ln1b + 32 + quad * 8 + 4);

    f16x8 a0A = {0,0,0,0,0,0,0,0}, a1A = {0,0,0,0,0,0,0,0};
    f16x8 a0B = {0,0,0,0,0,0,0,0}, a1B = {0,0,0,0,0,0,0,0};

    if (imgA) {
        float s  = 0.f, s2 = 0.f;
#pragma unroll
        for (int i = 0; i < 4; ++i)
#pragma unroll
            for (int r = 0; r < 4; ++r) { s += fA[i][r]; s2 += fA[i][r] * fA[i][r]; }
        s  += __shfl_xor(s, 16);  s  += __shfl_xor(s, 32);
        s2 += __shfl_xor(s2, 16); s2 += __shfl_xor(s2, 32);
        float mean = s * 0.015625f;
        float var  = s2 * 0.015625f - mean * mean;
        float rs   = rsqrtf(var + 1e-6f);
        float mrs  = mean * rs;
        uint4_t ra, rb;
#define LNP(va,vb,ga,gb,ca,cb) h2u(pkrtz(((va)*rs - mrs)*(ga) + (ca), ((vb)*rs - mrs)*(gb) + (cb)))
        ra[0] = LNP(fA[0][0],fA[0][1],g0[0],g0[1],c0[0],c0[1]);
        ra[1] = LNP(fA[0][2],fA[0][3],g0[2],g0[3],c0[2],c0[3]);
        ra[2] = LNP(fA[1][0],fA[1][1],g1[0],g1[1],c1[0],c1[1]);
        ra[3] = LNP(fA[1][2],fA[1][3],g1[2],g1[3],c1[2],c1[3]);
        rb[0] = LNP(fA[2][0],fA[2][1],g2[0],g2[1],c2[0],c2[1]);
        rb[1] = LNP(fA[2][2],fA[2][3],g2[2],g2[3],c2[2],c2[3]);
        rb[2] = LNP(fA[3][0],fA[3][1],g3[0],g3[1],c3[0],c3[1]);
        rb[3] = LNP(fA[3][2],fA[3][3],g3[2],g3[3],c3[2],c3[3]);
        a0A = __builtin_bit_cast(f16x8, ra);
        a1A = __builtin_bit_cast(f16x8, rb);
    }
    if (imgB) {
        float s  = 0.f, s2 = 0.f;
#pragma unroll
        for (int i = 0; i < 4; ++i)
#pragma unroll
            for (int r = 0; r < 4; ++r) { s += fB[i][r]; s2 += fB[i][r] * fB[i][r]; }
        s  += __shfl_xor(s, 16);  s  += __shfl_xor(s, 32);
        s2 += __shfl_xor(s2, 16); s2 += __shfl_xor(s2, 32);
        float mean = s * 0.015625f;
        float var  = s2 * 0.015625f - mean * mean;
        float rs   = rsqrtf(var + 1e-6f);
        float mrs  = mean * rs;
        uint4_t ra, rb;
        ra[0] = LNP(fB[0][0],fB[0][1],g0[0],g0[1],c0[0],c0[1]);
        ra[1] = LNP(fB[0][2],fB[0][3],g0[2],g0[3],c0[2],c0[3]);
        ra[2] = LNP(fB[1][0],fB[1][1],g1[0],g1[1],c1[0],c1[1]);
        ra[3] = LNP(fB[1][2],fB[1][3],g1[2],g1[3],c1[2],c1[3]);
        rb[0] = LNP(fB[2][0],fB[2][1],g2[0],g2[1],c2[0],c2[1]);
        rb[1] = LNP(fB[2][2],fB[2][3],g2[2],g2[3],c2[2],c2[3]);
        rb[2] = LNP(fB[3][0],fB[3][1],g3[0],g3[1],c3[0],c3[1]);
        rb[3] = LNP(fB[3][2],fB[3][3],g3[2],g3[3],c3[2],c3[3]);
#undef LNP
        a0B = __builtin_bit_cast(f16x8, ra);
        a1B = __builtin_bit_cast(f16x8, rb);
    }

    // MFMA: each w1t/b1 fragment loaded once, feeds both slots
    char* uhc = (char*)uh;
#pragma unroll
    for (int cot = 0; cot < 8; ++cot) {
        const int cob = (cot < 4) ? (cs * 64 + cot * 16) : (128 + cs * 64 + (cot - 4) * 16);
        const f16x8 wlo = __builtin_bit_cast(f16x8, *(const uint4_t*)(w1t + (cob + m) * 64 + quad * 8));
        const f16x8 whi = __builtin_bit_cast(f16x8, *(const uint4_t*)(w1t + (cob + m) * 64 + 32 + quad * 8));
        const f32x4 bv = *(const f32x4*)(b1 + cob + quad * 4);
        {
            f32x4 acc = {0.f,0.f,0.f,0.f};
            acc = __builtin_amdgcn_mfma_f32_16x16x32_f16(wlo, a0A, acc, 0, 0, 0);
            acc = __builtin_amdgcn_mfma_f32_16x16x32_f16(whi, a1A, acc, 0, 0, 0);
            uint2_t pk;
            pk[0] = imgA ? h2u(pkrtz(acc[0] + bv[0], acc[1] + bv[1])) : 0u;
            pk[1] = imgA ? h2u(pkrtz(acc[2] + bv[2], acc[3] + bv[3])) : 0u;
            int off = (pA * 256 + cot * 32 + quad * 8) ^ ((pA & 7) << 4);
            *(uint2_t*)(uhc + off) = pk;
        }
        if (aliveB) {
            f32x4 acc = {0.f,0.f,0.f,0.f};
            acc = __builtin_amdgcn_mfma_f32_16x16x32_f16(wlo, a0B, acc, 0, 0, 0);
            acc = __builtin_amdgcn_mfma_f32_16x16x32_f16(whi, a1B, acc, 0, 0, 0);
            if (pB < 100) {
                uint2_t pk;
                pk[0] = imgB ? h2u(pkrtz(acc[0] + bv[0], acc[1] + bv[1])) : 0u;
                pk[1] = imgB ? h2u(pkrtz(acc[2] + bv[2], acc[3] + bv[3])) : 0u;
                int off = (pB * 256 + cot * 32 + quad * 8) ^ ((pB & 7) << 4);
                *(uint2_t*)(uhc + off) = pk;
            }
        }
    }
    __syncthreads();

    // ---- phase 2: dw3x3 + gate, packed fp16 ----
    const int y = lane >> 3, xx = lane & 7;
    const int cq = wave;
    const int gc0 = cs * 64 + cq * 16;
    const long gpx = ((long)(b * 256 + ty * 8 + y) * 256) + tx * 8 + xx;

    h2 A1[8], A2[8];
#pragma unroll
    for (int j = 0; j < 8; ++j) {
        A1[j] = u2h(0u);
        A2[j] = u2h(0u);
    }
#pragma unroll
    for (int dy = 0; dy < 3; ++dy)
#pragma unroll
    for (int dx = 0; dx < 3; ++dx) {
        int h = (y + dy) * 10 + (xx + dx);
        int sw = (h & 7) << 4;
        int b0 = h * 256 + cq * 32;
        uint4_t u1l  = *(const uint4_t*)(uhc + ((b0)       ^ sw));
        uint4_t u1h  = *(const uint4_t*)(uhc + ((b0 + 16)  ^ sw));
        uint4_t u2l  = *(const uint4_t*)(uhc + ((b0 + 128) ^ sw));
        uint4_t u2hv = *(const uint4_t*)(uhc + ((b0 + 144) ^ sw));
        const uint4_t* wp = (const uint4_t*)(dwh + (dy * 3 + dx) * 256 + gc0);
        const uint4_t* vp = (const uint4_t*)(dwh + (dy * 3 + dx) * 256 + 128 + gc0);
        uint4_t w1l = wp[0], w1h = wp[1];
        uint4_t w2l = vp[0], w2h = vp[1];
#pragma unroll
        for (int j = 0; j < 4; ++j) {
            A1[j]     += u2h(u1l[j])  * u2h(w1l[j]);
            A1[j + 4] += u2h(u1h[j])  * u2h(w1h[j]);
            A2[j]     += u2h(u2l[j])  * u2h(w2l[j]);
            A2[j + 4] += u2h(u2hv[j]) * u2h(w2h[j]);
        }
    }
    const uint4_t* bp1 = (const uint4_t*)(dbh + gc0);
    const uint4_t* bp2 = (const uint4_t*)(dbh + 128 + gc0);
    uint4_t b1l = bp1[0], b1h = bp1[1];
    uint4_t b2l = bp2[0], b2h = bp2[1];
    uint4_t s0, s1;
#pragma unroll
    for (int j = 0; j < 4; ++j) {
        h2 t0 = (A1[j]     + u2h(b1l[j])) * (A2[j]     + u2h(b2l[j]));
        h2 t1 = (A1[j + 4] + u2h(b1h[j])) * (A2[j + 4] + u2h(b2h[j]));
        s0[j] = h2u(t0);
        s1[j] = h2u(t1);
    }
    *(uint4_t*)(t + gpx * 128 + gc0)     = s0;
    *(uint4_t*)(t + gpx * 128 + gc0 + 8) = s1;
}

// ---------- K_R: GAP over t (b128 loads, 2048 blocks) ----------
__global__ __launch_bounds__(256) void k_red(
    const short* __restrict__ t, float* __restrict__ gpart)
{
    __shared__ float red[16][16][8];   // [pr][cg][j]  8 KB
    const int blk = blockIdx.x;        // 2048 = 8 batch x 256 slices
    const int tid = threadIdx.x;
    const int cg = tid & 15;
    const int pr = tid >> 4;
    const short* tb = t + (long)blk * 256 * 128 + cg * 8;
    float a0=0,a1=0,a2=0,a3=0,a4=0,a5=0,a6=0,a7=0;
#pragma unroll 4
    for (int it = 0; it < 16; ++it) {
        uint4_t u = *(const uint4_t*)(tb + (long)(it * 16 + pr) * 128);
        h2 v0=u2h(u[0]), v1=u2h(u[1]), v2=u2h(u[2]), v3=u2h(u[3]);
        a0 += (float)v0[0]; a1 += (float)v0[1]; a2 += (float)v1[0]; a3 += (float)v1[1];
        a4 += (float)v2[0]; a5 += (float)v2[1]; a6 += (float)v3[0]; a7 += (float)v3[1];
    }
    red[pr][cg][0]=a0; red[pr][cg][1]=a1; red[pr][cg][2]=a2; red[pr][cg][3]=a3;
    red[pr][cg][4]=a4; red[pr][cg][5]=a5; red[pr][cg][6]=a6; red[pr][cg][7]=a7;
    __syncthreads();
    if (tid < 128) {
        int g = tid >> 3, j = tid & 7;
        float s = 0.f;
#pragma unroll
        for (int r = 0; r < 16; ++r) s += red[r][g][j];
        gpart[(long)blk * 128 + tid] = s;
    }
}

// ---------- K_S: final GAP + SCA (one block per batch) ----------
__global__ __launch_bounds__(256) void k_sca2(
    const float* __restrict__ gpart, const float* __restrict__ scaw,
    const float* __restrict__ scab, float* __restrict__ watt)
{
    __shared__ float gl[256];
    __shared__ float gn[128];
    const int b = blockIdx.x;
    const int tid = threadIdx.x;
    const int c = tid & 127, half = tid >> 7;
    float s = 0.f;
    const float* gp = gpart + (long)b * 256 * 128 + c;
    for (int i = half; i < 256; i += 2) s += gp[(long)i * 128];
    gl[half * 128 + c] = s;
    __syncthreads();
    if (tid < 128) gn[c] = (gl[c] + gl[128 + c]) * (1.0f / 65536.0f);
    __syncthreads();
    if (tid < 128) {
        float acc = scab[c];
        for (int ci = 0; ci < 128; ++ci) acc += gn[ci] * scaw[ci * 128 + c];
        watt[b * 128 + c] = acc;
    }
}

// ---------- K_B: pw2 + residual + LN2 + pw3 + gate + pw4 + residual ----------
// xl/zt are PER-WAVE-PRIVATE slabs: no __syncthreads needed anywhere —
// each wave's LDS write->read ordering is handled by lgkmcnt.
#define XLST 72
#define ZTST 136
__global__ __launch_bounds__(256) void k_b(
    const short* __restrict__ t, const float* __restrict__ watt,
    const short* __restrict__ w2t, const float* __restrict__ b2,
    const float* __restrict__ x, const float* __restrict__ beta,
    const float* __restrict__ ln2g, const float* __restrict__ ln2b,
    const short* __restrict__ w3t, const float* __restrict__ b3,
    const short* __restrict__ w4t, const float* __restrict__ b4,
    const float* __restrict__ gamma, float* __restrict__ out)
{
    __shared__ short xl[4][16 * XLST];
    __shared__ short zt[4][16 * ZTST];
    const int lane = threadIdx.x & 63;
    const int wave = threadIdx.x >> 6;
    const int m = lane & 15, quad = lane >> 4;
    const long px0 = (long)blockIdx.x * 64 + wave * 16;
    const int b = (int)(px0 >> 16);
    const float* wa = watt + b * 128;

    // residual x loads first: latency hides under t-load + pw2 MFMA
    f32x4 xv[4];
#pragma unroll
    for (int nt = 0; nt < 4; ++nt)
        xv[nt] = *(const f32x4*)(x + (px0 + m) * 64 + nt * 16 + quad * 4);

    const short* tr = t + (px0 + m) * 128;
    f16x8 bfr[4];
#pragma unroll
    for (int kh = 0; kh < 4; ++kh) {
        uint4_t tvv = *(const uint4_t*)(tr + kh * 32 + quad * 8);
        f32x4 w0  = *(const f32x4*)(wa + kh * 32 + quad * 8);
        f32x4 w1v = *(const f32x4*)(wa + kh * 32 + quad * 8 + 4);
        uint4_t o;
        o[0] = h2u(u2h(tvv[0]) * pkrtz(w0[0],  w0[1]));
        o[1] = h2u(u2h(tvv[1]) * pkrtz(w0[2],  w0[3]));
        o[2] = h2u(u2h(tvv[2]) * pkrtz(w1v[0], w1v[1]));
        o[3] = h2u(u2h(tvv[3]) * pkrtz(w1v[2], w1v[3]));
        bfr[kh] = __builtin_bit_cast(f16x8, o);
    }
    f32x4 acc2[4];
#pragma unroll
    for (int nt = 0; nt < 4; ++nt) { f32x4 z = {0.f,0.f,0.f,0.f}; acc2[nt] = z; }
#pragma unroll
    for (int nt = 0; nt < 4; ++nt)
#pragma unroll
        for (int kh = 0; kh < 4; ++kh) {
            f16x8 aw = __builtin_bit_cast(f16x8,
                *(const uint4_t*)(w2t + (nt * 16 + m) * 128 + kh * 32 + quad * 8));
            acc2[nt] = __builtin_amdgcn_mfma_f32_16x16x32_f16(aw, bfr[kh], acc2[nt], 0, 0, 0);
        }
    float x1v[4][4];
#pragma unroll
    for (int nt = 0; nt < 4; ++nt) {
        int cob = nt * 16 + quad * 4;
        f32x4 bb = *(const f32x4*)(b2 + cob);
        f32x4 be = *(const f32x4*)(beta + cob);
#pragma unroll
        for (int r = 0; r < 4; ++r)
            x1v[nt][r] = xv[nt][r] + (acc2[nt][r] + bb[r]) * be[r];
    }
    float s = 0.f, s2 = 0.f;
#pragma unroll
    for (int nt = 0; nt < 4; ++nt)
#pragma unroll
        for (int r = 0; r < 4; ++r) { s += x1v[nt][r]; s2 += x1v[nt][r] * x1v[nt][r]; }
    s  += __shfl_xor(s, 16);  s  += __shfl_xor(s, 32);
    s2 += __shfl_xor(s2, 16); s2 += __shfl_xor(s2, 32);
    float mean = s * 0.015625f;
    float var  = s2 * 0.015625f - mean * mean;
    float rs   = rsqrtf(var + 1e-6f);
    float mrs  = mean * rs;
#pragma unroll
    for (int nt = 0; nt < 4; ++nt) {
        int cob = nt * 16 + quad * 4;
        f32x4 gg = *(const f32x4*)(ln2g + cob);
        f32x4 cc = *(const f32x4*)(ln2b + cob);
        float v0 = (x1v[nt][0] * rs - mrs) * gg[0] + cc[0];
        float v1 = (x1v[nt][1] * rs - mrs) * gg[1] + cc[1];
        float v2 = (x1v[nt][2] * rs - mrs) * gg[2] + cc[2];
        float v3 = (x1v[nt][3] * rs - mrs) * gg[3] + cc[3];
        uint2_t pk;
        pk[0] = h2u(pkrtz(v0, v1));
        pk[1] = h2u(pkrtz(v2, v3));
        *(uint2_t*)&xl[wave][m * XLST + cob] = pk;
    }
    // no barrier: xl[wave] is wave-private; lgkmcnt orders write->read
    f16x8 xb0 = __builtin_bit_cast(f16x8, *(const uint4_t*)&xl[wave][m * XLST + quad * 8]);
    f16x8 xb1 = __builtin_bit_cast(f16x8, *(const uint4_t*)&xl[wave][m * XLST + 32 + quad * 8]);
#pragma unroll
    for (int pg = 0; pg < 8; ++pg) {
        f32x4 aA = {0.f,0.f,0.f,0.f}, aB = {0.f,0.f,0.f,0.f};
        f16x8 w3a0 = __builtin_bit_cast(f16x8, *(const uint4_t*)(w3t + (pg * 16 + m) * 64 + quad * 8));
        f16x8 w3a1 = __builtin_bit_cast(f16x8, *(const uint4_t*)(w3t + (pg * 16 + m) * 64 + 32 + quad * 8));
        f16x8 w3b0 = __builtin_bit_cast(f16x8, *(const uint4_t*)(w3t + (128 + pg * 16 + m) * 64 + quad * 8));
        f16x8 w3b1 = __builtin_bit_cast(f16x8, *(const uint4_t*)(w3t + (128 + pg * 16 + m) * 64 + 32 + quad * 8));
        aA = __builtin_amdgcn_mfma_f32_16x16x32_f16(w3a0, xb0, aA, 0, 0, 0);
        aA = __builtin_amdgcn_mfma_f32_16x16x32_f16(w3a1, xb1, aA, 0, 0, 0);
        aB = __builtin_amdgcn_mfma_f32_16x16x32_f16(w3b0, xb0, aB, 0, 0, 0);
        aB = __builtin_amdgcn_mfma_f32_16x16x32_f16(w3b1, xb1, aB, 0, 0, 0);
        int cb = pg * 16 + quad * 4;
        f32x4 bA = *(const f32x4*)(b3 + cb);
        f32x4 bB = *(const f32x4*)(b3 + 128 + cb);
        float p0 = (aA[0] + bA[0]) * (aB[0] + bB[0]);
        float p1 = (aA[1] + bA[1]) * (aB[1] + bB[1]);
        float p2 = (aA[2] + bA[2]) * (aB[2] + bB[2]);
        float p3 = (aA[3] + bA[3]) * (aB[3] + bB[3]);
        uint2_t pk;
        pk[0] = h2u(pkrtz(p0, p1));
        pk[1] = h2u(pkrtz(p2, p3));
        *(uint2_t*)&zt[wave][m * ZTST + cb] = pk;
    }
    // no barrier: zt[wave] is wave-private
    f16x8 zb[4];
#pragma unroll
    for (int kh = 0; kh < 4; ++kh)
        zb[kh] = __builtin_bit_cast(f16x8, *(const uint4_t*)&zt[wave][m * ZTST + kh * 32 + quad * 8]);
    f32x4 acc4[4];
#pragma unroll
    for (int nt = 0; nt < 4; ++nt) { f32x4 z = {0.f,0.f,0.f,0.f}; acc4[nt] = z; }
#pragma unroll
    for (int nt = 0; nt < 4; ++nt)
#pragma unroll
        for (int kh = 0; kh < 4; ++kh) {
            f16x8 aw = __builtin_bit_cast(f16x8,
                *(const uint4_t*)(w4t + (nt * 16 + m) * 128 + kh * 32 + quad * 8));
            acc4[nt] = __builtin_amdgcn_mfma_f32_16x16x32_f16(aw, zb[kh], acc4[nt], 0, 0, 0);
        }
#pragma unroll
    for (int nt = 0; nt < 4; ++nt) {
        int cob = nt * 16 + quad * 4;
        f32x4 bb = *(const f32x4*)(b4 + cob);
        f32x4 gm = *(const f32x4*)(gamma + cob);
        f32x4 o;
#pragma unroll
        for (int r = 0; r < 4; ++r)
            o[r] = x1v[nt][r] + (acc4[nt][r] + bb[r]) * gm[r];
        *(f32x4*)(out + (px0 + m) * 64 + cob) = o;
    }
}

// ---------- launch ----------
extern "C" void kernel_launch(void* const* d_in, const int* in_sizes, int n_in,
                              void* d_out, int out_size, void* d_ws, size_t ws_size,
                              hipStream_t stream) {
    (void)in_sizes; (void)n_in; (void)out_size; (void)ws_size;
    const float* x    = (const float*)d_in[0];
    const float* ln1g = (const float*)d_in[1];
    const float* ln1b = (const float*)d_in[2];
    const float* pw1w = (const float*)d_in[3];
    const float* pw1b = (const float*)d_in[4];
    const float* dww  = (const float*)d_in[5];
    const float* dwb  = (const float*)d_in[6];
    const float* scaw = (const float*)d_in[7];
    const float* scab = (const float*)d_in[8];
    const float* pw2w = (const float*)d_in[9];
    const float* pw2b = (const float*)d_in[10];
    const float* beta = (const float*)d_in[11];
    const float* ln2g = (const float*)d_in[12];
    const float* ln2b = (const float*)d_in[13];
    const float* pw3w = (const float*)d_in[14];
    const float* pw3b = (const float*)d_in[15];
    const float* pw4w = (const float*)d_in[16];
    const float* pw4b = (const float*)d_in[17];
    const float* gamma= (const float*)d_in[18];

    char* ws = (char*)d_ws;
    short* w1t = (short*)(ws + OFF_W1T);
    short* w2t = (short*)(ws + OFF_W2T);
    short* w3t = (short*)(ws + OFF_W3T);
    short* w4t = (short*)(ws + OFF_W4T);
    short* dwh = (short*)(ws + OFF_DWH);
    short* dbh = (short*)(ws + OFF_DBH);
    float* watt = (float*)(ws + OFF_WATT);
    float* gpart = (float*)(ws + OFF_GPART);
    short* t   = (short*)(ws + OFF_T);
    float* out = (float*)d_out;

    k_prep<<<64, 256, 0, stream>>>(pw1w, pw2w, pw3w, pw4w, dww, dwb,
                                   w1t, w2t, w3t, w4t, dwh, dbh);
    k_a<<<16384, 256, 0, stream>>>(x, ln1g, ln1b, w1t, pw1b, dwh, dbh, t);
    k_red<<<2048, 256, 0, stream>>>(t, gpart);
    k_sca2<<<8, 256, 0, stream>>>(gpart, scaw, scab, watt);
    k_b<<<8192, 256, 0, stream>>>(t, watt, w2t, pw2b, x, beta, ln2g, ln2b,
                                  w3t, pw3b, w4t, pw4b, gamma, out);
}